// Round 18
// baseline (214.668 us; speedup 1.0000x reference)
//
#include <hip/hip_runtime.h>
#include <hip/hip_bf16.h>
#include <math.h>

static constexpr int T_TOK = 16384;   // 4*4096 tokens
static constexpr int E     = 256;     // experts
static constexpr int H     = 2048;    // hidden dim

typedef __attribute__((ext_vector_type(8))) _Float16       f16x8;
typedef __attribute__((ext_vector_type(8))) unsigned short u16x8;
typedef __attribute__((ext_vector_type(4))) float          f32x4;

// 2-way f16 split of a PRE-SCALED value: xs == h + m + eps, |eps| <~ 2^-22|xs|.
__device__ __forceinline__ void split2(float xs, unsigned short& h,
                                       unsigned short& m) {
    _Float16 hh = (_Float16)xs;        // RN f32->f16
    float fh = (float)hh;
    float r  = xs - fh;                // exact in f32
    _Float16 mm = (_Float16)r;         // RN
    h = *(unsigned short*)&hh; m = *(unsigned short*)&mm;
}

// ---------------------------------------------------------------------------
// Kernel 0: split W*256 [256][2048] fp32 into two f16 planes (same layout).
// ---------------------------------------------------------------------------
__global__ __launch_bounds__(256) void prep_w(const float* __restrict__ W,
                                              unsigned short* __restrict__ Wh,
                                              unsigned short* __restrict__ Wm) {
    const int i = (blockIdx.x * 256 + threadIdx.x) * 4;
    float4 x = *(const float4*)(W + i);
    unsigned short h[4], m[4];
    split2(x.x * 256.f, h[0], m[0]);
    split2(x.y * 256.f, h[1], m[1]);
    split2(x.z * 256.f, h[2], m[2]);
    split2(x.w * 256.f, h[3], m[3]);
#pragma unroll
    for (int q = 0; q < 4; ++q) { Wh[i+q] = h[q]; Wm[i+q] = m[q]; }
}

// ---------------------------------------------------------------------------
// Kernel 1: partial logits via f16x2 MFMA, THREE passes (hh,hm,mh).
// BARRIER-FREE, LDS-FREE design (round-18): W's f16 planes are 2 MB ->
// fully L2-resident; X is streamed once. Each wave is an INDEPENDENT
// 64-token x 32-expert GEMM worker reading operands straight from cache.
// Block = 512 thr = 8 waves = one 64-token tile x all 256 experts:
//   - all 8 waves read the SAME A data (16 KB/step working set -> L1-hit
//     after the first toucher); X HBM traffic exactly once;
//   - B frags per-lane from L2 (W resident);
//   - A-load pattern: lanes cover full 16-row x 128 B blocks per float4
//     pair -> no overfetch;
//   - zero barriers/LDS/bank-conflicts; compiler hoists loads across
//     steps freely; waves never wait on each other.
// Per wave per step (BK=64): 16 A-float4 + 8 B-f16x8 loads, 64 split2,
// 48 MFMA. Frag mapping and numerics identical to the passing R17 kernel.
// ---------------------------------------------------------------------------
__global__ __launch_bounds__(512) void gemm_logits(
        const float* __restrict__ X,
        const unsigned short* __restrict__ Wh,
        const unsigned short* __restrict__ Wm,
        float* __restrict__ Cp, int klen) {
    const int tid  = threadIdx.x;
    const int lane = tid & 63;
    const int wv   = tid >> 6;            // 0..7  -> expert tile (32 wide)
    const int frow = lane & 15;
    const int fkc  = lane >> 4;           // 0..3  -> 8-float k sub-chunk
    const int kz   = blockIdx.y;          // split-K chunk
    const int kbase = kz * klen;
    const int TB   = blockIdx.x * 64;     // token tile (64 tall)
    const int eb   = wv * 32;             // wave-private expert base

    // per-lane base pointers (k part: +fkc*8; step adds kt*64 + s*32)
    const float* pA0 = X + (size_t)(TB +  0 + frow) * H + kbase + fkc * 8;
    const float* pA1 = X + (size_t)(TB + 16 + frow) * H + kbase + fkc * 8;
    const float* pA2 = X + (size_t)(TB + 32 + frow) * H + kbase + fkc * 8;
    const float* pA3 = X + (size_t)(TB + 48 + frow) * H + kbase + fkc * 8;
    const unsigned short* pBh0 = Wh + (size_t)(eb +  0 + frow) * H + kbase + fkc * 8;
    const unsigned short* pBh1 = Wh + (size_t)(eb + 16 + frow) * H + kbase + fkc * 8;
    const unsigned short* pBm0 = Wm + (size_t)(eb +  0 + frow) * H + kbase + fkc * 8;
    const unsigned short* pBm1 = Wm + (size_t)(eb + 16 + frow) * H + kbase + fkc * 8;

    f32x4 acc[4][2];
#pragma unroll
    for (int i = 0; i < 4; ++i)
#pragma unroll
        for (int j = 0; j < 2; ++j) acc[i][j] = (f32x4){0.f, 0.f, 0.f, 0.f};

    const int NK = klen / 64;             // nsplit 4/2/1 -> 8/16/32

#pragma unroll 2
    for (int kt = 0; kt < NK; ++kt) {
#pragma unroll
        for (int s = 0; s < 2; ++s) {
            const int ko = kt * 64 + s * 32;   // float / u16 element offset

            // ---- B frags straight from L2 (W planes resident)
            f16x8 bh[2], bm[2];
            bh[0] = *(const f16x8*)(pBh0 + ko);
            bh[1] = *(const f16x8*)(pBh1 + ko);
            bm[0] = *(const f16x8*)(pBm0 + ko);
            bm[1] = *(const f16x8*)(pBm1 + ko);

            // ---- A frags: load 8 floats per i, split2 in-register
            f16x8 ah[4], am[4];
#pragma unroll
            for (int i = 0; i < 4; ++i) {
                const float* pa = (i == 0) ? pA0 : (i == 1) ? pA1
                                 : (i == 2) ? pA2 : pA3;
                float4 q0 = *(const float4*)(pa + ko);
                float4 q1 = *(const float4*)(pa + ko + 4);
                float xv[8] = {q0.x, q0.y, q0.z, q0.w, q1.x, q1.y, q1.z, q1.w};
                u16x8 vh, vm;
#pragma unroll
                for (int t = 0; t < 8; ++t) {
                    unsigned short h, m;
                    split2(xv[t] * 64.f, h, m);
                    vh[t] = h; vm[t] = m;
                }
                ah[i] = *(f16x8*)&vh;
                am[i] = *(f16x8*)&vm;
            }

            // ---- 24 MFMA: hh, hm, mh
            __builtin_amdgcn_s_setprio(1);
#pragma unroll
            for (int i = 0; i < 4; ++i)
#pragma unroll
                for (int j = 0; j < 2; ++j)
                    acc[i][j] = __builtin_amdgcn_mfma_f32_16x16x32_f16(
                        ah[i], bh[j], acc[i][j], 0, 0, 0);     // hh
#pragma unroll
            for (int i = 0; i < 4; ++i)
#pragma unroll
                for (int j = 0; j < 2; ++j)
                    acc[i][j] = __builtin_amdgcn_mfma_f32_16x16x32_f16(
                        ah[i], bm[j], acc[i][j], 0, 0, 0);     // hm
#pragma unroll
            for (int i = 0; i < 4; ++i)
#pragma unroll
                for (int j = 0; j < 2; ++j)
                    acc[i][j] = __builtin_amdgcn_mfma_f32_16x16x32_f16(
                        am[i], bh[j], acc[i][j], 0, 0, 0);     // mh
            __builtin_amdgcn_s_setprio(0);
        }
    }

    // ---- epilogue: D layout col=lane&15, row=(lane>>4)*4+r
    float* Cz = Cp + (size_t)kz * T_TOK * E;
    const int rbase = (lane >> 4) * 4;
#pragma unroll
    for (int i = 0; i < 4; ++i)
#pragma unroll
        for (int j = 0; j < 2; ++j) {
            const int ecol = eb + j * 16 + frow;
#pragma unroll
            for (int r = 0; r < 4; ++r) {
                const int tok = TB + i * 16 + rbase + r;
                Cz[(size_t)tok * E + ecol] = acc[i][j][r];
            }
        }
}

// ---------------------------------------------------------------------------
// Kernel 2: fused split-K reduce + routing (proven). 16 lanes/token, 16
// experts/lane, all in registers; exact lax.top_k tie-breaks. Logits are
// scaled by 2^14 (X*64, W*256) -> multiply by 2^-14 (exact) before sigmoid.
// ---------------------------------------------------------------------------
__global__ __launch_bounds__(256) void route_kernel(const float* __restrict__ P,
                                                    const float* __restrict__ bias,
                                                    float* __restrict__ out,
                                                    int nsplit) {
    const int sub = threadIdx.x & 15;
    const int tok = blockIdx.x * 16 + (threadIdx.x >> 4);
    const int ebase = sub * 16;

    double accd[16];
#pragma unroll
    for (int i = 0; i < 16; ++i) accd[i] = 0.0;
    for (int s = 0; s < nsplit; ++s) {
        const float* base = P + (size_t)s * T_TOK * E + (size_t)tok * E + ebase;
#pragma unroll
        for (int v = 0; v < 4; ++v) {
            float4 f = *(const float4*)(base + v * 4);
            accd[v * 4 + 0] += (double)f.x; accd[v * 4 + 1] += (double)f.y;
            accd[v * 4 + 2] += (double)f.z; accd[v * 4 + 3] += (double)f.w;
        }
    }

    float us[16], sc[16];
#pragma unroll
    for (int i = 0; i < 16; ++i) {
        float lg = (float)accd[i] * (1.f / 16384.f);   // exact pow2 unscale
        double s = 1.0 / (1.0 + exp(-(double)lg));
        us[i] = (float)s;
        sc[i] = us[i] + bias[ebase + i];
    }

    float m1 = -1e30f, m2 = -1e30f;
#pragma unroll
    for (int i = 0; i < 16; ++i) {
        float s = sc[i];
        if (s > m1)      { m2 = m1; m1 = s; }
        else if (s > m2) { m2 = s; }
    }
    float pm1 = __shfl_xor(m1, 1, 16);
    float pm2 = __shfl_xor(m2, 1, 16);
    float gsum = (m1 >= pm1) ? (m1 + fmaxf(m2, pm1)) : (pm1 + fmaxf(pm2, m1));

    const int g = sub >> 1;
    int rank = 0;
#pragma unroll
    for (int h = 0; h < 8; ++h) {
        float gh = __shfl(gsum, h * 2, 16);
        if (h != g && (gh > gsum || (gh == gsum && h < g))) ++rank;
    }
    const bool sel = (rank < 4);

    unsigned used = 0;
    float myoi = 0.f, myow = 0.f;
    float wsum = 0.f;
#pragma unroll
    for (int p = 0; p < 8; ++p) {
        float bv = -1e30f; int bi = 0x7fff; float bu = 0.f;
#pragma unroll
        for (int i = 0; i < 16; ++i) {
            float v = ((used >> i) & 1u) ? -1e30f : (sel ? sc[i] : 0.0f);
            if (v > bv || (v == bv && (ebase + i) < bi)) {
                bv = v; bi = ebase + i; bu = us[i];
            }
        }
#pragma unroll
        for (int d = 1; d < 16; d <<= 1) {
            float ov = __shfl_xor(bv, d, 16);
            int   oi = __shfl_xor(bi, d, 16);
            float ou = __shfl_xor(bu, d, 16);
            if (ov > bv || (ov == bv && oi < bi)) { bv = ov; bi = oi; bu = ou; }
        }
        if ((bi >> 4) == sub) used |= 1u << (bi & 15);
        if (sub == p) { myoi = (float)bi; myow = bu; }
        wsum += bu;
    }

    const float scale = 2.5f / (wsum + 1e-20f);
    if (sub < 8) {
        out[(size_t)tok * 8 + sub] = myoi;
        out[(size_t)T_TOK * 8 + (size_t)tok * 8 + sub] = myow * scale;
    }
}

// ---------------------------------------------------------------------------
extern "C" void kernel_launch(void* const* d_in, const int* in_sizes, int n_in,
                              void* d_out, int out_size, void* d_ws, size_t ws_size,
                              hipStream_t stream) {
    const float* X = (const float*)d_in[0];   // [4,4096,2048] fp32
    const float* W = (const float*)d_in[1];   // [256,2048]   fp32
    const float* B = (const float*)d_in[2];   // [256]        fp32
    float* out     = (float*)d_out;

    const size_t WE     = (size_t)E * H;                       // 524288
    const size_t planeB = WE * sizeof(unsigned short);         // 1 MB
    const size_t chunkB = (size_t)T_TOK * E * sizeof(float);   // 16 MB

    unsigned short* Wh = (unsigned short*)d_ws;
    unsigned short* Wm = Wh + WE;
    float* part = (float*)((char*)d_ws + 2 * planeB);

    int nsplit = 1;
    if (ws_size >= 2 * planeB + 4 * chunkB)      nsplit = 4;
    else if (ws_size >= 2 * planeB + 2 * chunkB) nsplit = 2;
    const int klen = H / nsplit;

    prep_w<<<WE / (256 * 4), 256, 0, stream>>>(W, Wh, Wm);

    dim3 gg(T_TOK / 64, nsplit);              // (256, 4) = 1024 blocks x 512
    gemm_logits<<<gg, 512, 0, stream>>>(X, Wh, Wm, part, klen);

    route_kernel<<<T_TOK / 16, 256, 0, stream>>>(part, B, out, nsplit);
}

// Round 19
// 104.160 us; speedup vs baseline: 2.0609x; 2.0609x over previous
//
#include <hip/hip_runtime.h>
#include <hip/hip_bf16.h>
#include <math.h>

static constexpr int T_TOK = 16384;   // 4*4096 tokens
static constexpr int E     = 256;     // experts
static constexpr int H     = 2048;    // hidden dim

typedef __attribute__((ext_vector_type(8))) _Float16       f16x8;
typedef __attribute__((ext_vector_type(8))) unsigned short u16x8;
typedef __attribute__((ext_vector_type(4))) float          f32x4;

// 2-way f16 split of a PRE-SCALED value: xs == h + m + eps, |eps| <~ 2^-22|xs|.
__device__ __forceinline__ void split2(float xs, unsigned short& h,
                                       unsigned short& m) {
    _Float16 hh = (_Float16)xs;        // RN f32->f16
    float fh = (float)hh;
    float r  = xs - fh;                // exact in f32
    _Float16 mm = (_Float16)r;         // RN
    h = *(unsigned short*)&hh; m = *(unsigned short*)&mm;
}

// async 16B global -> LDS (dest = wave-uniform base + lane*16)
__device__ __forceinline__ void gload_lds16(const unsigned short* g,
                                            unsigned short* l) {
    __builtin_amdgcn_global_load_lds(
        (const __attribute__((address_space(1))) unsigned int*)g,
        (__attribute__((address_space(3))) unsigned int*)l, 16, 0, 0);
}

// ---------------------------------------------------------------------------
// Kernel 0: split W*256 [256][2048] fp32 into two f16 planes (same layout).
// ---------------------------------------------------------------------------
__global__ __launch_bounds__(256) void prep_w(const float* __restrict__ W,
                                              unsigned short* __restrict__ Wh,
                                              unsigned short* __restrict__ Wm) {
    const int i = (blockIdx.x * 256 + threadIdx.x) * 4;
    float4 x = *(const float4*)(W + i);
    unsigned short h[4], m[4];
    split2(x.x * 256.f, h[0], m[0]);
    split2(x.y * 256.f, h[1], m[1]);
    split2(x.z * 256.f, h[2], m[2]);
    split2(x.w * 256.f, h[3], m[3]);
#pragma unroll
    for (int q = 0; q < 4; ++q) { Wh[i+q] = h[q]; Wm[i+q] = m[q]; }
}

// ---------------------------------------------------------------------------
// Kernel 1: partial logits via f16x2 MFMA, THREE passes (hh,hm,mh).
// R17 structure (best measured: 95.5 us gemm) with nsplit=2:
//   - grid (2,128,2) = 512 blocks = EXACTLY 2 blocks/CU in one residency
//     wave (no 4-in-2-slots tail imbalance);
//   - split-K partial traffic halves (write 32 MB, route reads 32 MB).
// 512 thr = 8 waves (2M x 4N), wave tile 64x32, acc[4][2] = 32 AGPR.
// LDS [plane][8 kc][128][8] x2 = 64 KB, single-buffered, BK=64, NK=16.
// Step: sync1 -> 4 B gloads -> A_STAGE (16 floats split2, covers gloads)
// -> sync2 -> issue X(kt+1) (flies under the 48-MFMA phase; drained by
// NEXT step's sync1 after ~2000 cyc) -> 2 x (frag reads + 24 MFMA).
// R18 lesson hard-confirmed: frag operands MUST come from LDS (coalesced
// staging); per-lane strided global frag reads are a 64-line gather.
// ---------------------------------------------------------------------------
__global__ __launch_bounds__(512, 4) void gemm_logits(
        const float* __restrict__ X,
        const unsigned short* __restrict__ Wh,
        const unsigned short* __restrict__ Wm,
        float* __restrict__ Cp, int klen) {
    __shared__ __align__(16) unsigned short As[2][8][128][8];   // 32 KB
    __shared__ __align__(16) unsigned short Bs[2][8][128][8];   // 32 KB

    const int tid  = threadIdx.x;
    const int lane = tid & 63;
    const int wid  = tid >> 6;            // 0..7
    const int wm   = wid >> 2, wn = wid & 3;   // 2M x 4N; wave = 64 x 32
    const int kz   = blockIdx.z;
    const int kbase = kz * klen;
    const int TB   = blockIdx.y * 128;
    const int eb   = blockIdx.x * 128;

    // A staging: thread owns row=tid>>2, k-chunks sc and sc+4 (sc=tid&3)
    const int srow = tid >> 2;
    const int sc   = tid & 3;
    const float* Xp = X + (size_t)(TB + srow) * H + kbase + sc * 8;

    // B staging: 2 slots per plane: tid -> (kc=tid>>7, row=tid&127) and
    // tid+512 -> (kc+4, same row). Global source k offsets bkc*8 and +32.
    const int brow = tid & 127;
    const int bkc  = tid >> 7;            // 0..3
    const unsigned short* WB0 = Wh + (size_t)(eb + brow) * H + kbase + bkc * 8;
    const unsigned short* WB1 = Wm + (size_t)(eb + brow) * H + kbase + bkc * 8;
    const int eOffB0 = tid * 8;           // elements (16 B)
    const int eOffB1 = (tid + 512) * 8;   // kc+4, same row

    const int frow = lane & 15;
    const int fkc  = lane >> 4;           // k-chunk 0..3 within a 32-k half

    f32x4 acc[4][2];
#pragma unroll
    for (int i = 0; i < 4; ++i)
#pragma unroll
        for (int j = 0; j < 2; ++j) acc[i][j] = (f32x4){0.f, 0.f, 0.f, 0.f};

    const int NK = klen / 64;             // nsplit 2 -> 16

#define B_STAGE(KT)                                                            \
    {                                                                          \
        const int ko = (KT) * 64;                                              \
        gload_lds16(WB0 + ko,      &Bs[0][0][0][0] + eOffB0);                  \
        gload_lds16(WB0 + ko + 32, &Bs[0][0][0][0] + eOffB1);                  \
        gload_lds16(WB1 + ko,      &Bs[1][0][0][0] + eOffB0);                  \
        gload_lds16(WB1 + ko + 32, &Bs[1][0][0][0] + eOffB1);                  \
    }

    // ---- scale by 64, split2 the thread's 16 floats, write chunks sc, sc+4
#define A_STAGE()                                                              \
    {                                                                          \
        float xv[16] = {x0.x, x0.y, x0.z, x0.w, x1.x, x1.y, x1.z, x1.w,        \
                        x2.x, x2.y, x2.z, x2.w, x3.x, x3.y, x3.z, x3.w};       \
        u16x8 vh0, vm0, vh1, vm1;                                              \
        _Pragma("unroll")                                                      \
        for (int t = 0; t < 8; ++t) {                                          \
            unsigned short h, m;                                               \
            split2(xv[t] * 64.f, h, m);                                        \
            vh0[t] = h; vm0[t] = m;                                            \
        }                                                                      \
        _Pragma("unroll")                                                      \
        for (int t = 0; t < 8; ++t) {                                          \
            unsigned short h, m;                                               \
            split2(xv[8 + t] * 64.f, h, m);                                    \
            vh1[t] = h; vm1[t] = m;                                            \
        }                                                                      \
        *(u16x8*)&As[0][sc    ][srow][0] = vh0;                                \
        *(u16x8*)&As[1][sc    ][srow][0] = vm0;                                \
        *(u16x8*)&As[0][sc + 4][srow][0] = vh1;                                \
        *(u16x8*)&As[1][sc + 4][srow][0] = vm1;                                \
    }

#define X_LOAD(KT)                                                             \
    {                                                                          \
        const float* xn = Xp + (KT) * 64;                                      \
        x0 = *(const float4*)(xn + 0);   x1 = *(const float4*)(xn + 4);        \
        x2 = *(const float4*)(xn + 32);  x3 = *(const float4*)(xn + 36);       \
    }

    // ---- prologue: X(0) sync load
    float4 x0, x1, x2, x3;
    X_LOAD(0);

    for (int kt = 0; kt < NK; ++kt) {
        __syncthreads();              // prior frag reads done; X(kt) landed
        B_STAGE(kt);
        A_STAGE();                    // consumes X(kt); covers B gloads
        __syncthreads();              // B gloads + A writes visible
        if (kt + 1 < NK) X_LOAD(kt + 1);   // flies under the MFMA phase

#pragma unroll
        for (int s = 0; s < 2; ++s) {
            const int s4 = s * 4 + fkc;
            f16x8 afh[4], afm[4], bfh[2], bfm[2];
#pragma unroll
            for (int i = 0; i < 4; ++i) {
                afh[i] = *(const f16x8*)&As[0][s4][wm * 64 + i * 16 + frow][0];
                afm[i] = *(const f16x8*)&As[1][s4][wm * 64 + i * 16 + frow][0];
            }
#pragma unroll
            for (int j = 0; j < 2; ++j) {
                bfh[j] = *(const f16x8*)&Bs[0][s4][wn * 32 + j * 16 + frow][0];
                bfm[j] = *(const f16x8*)&Bs[1][s4][wn * 32 + j * 16 + frow][0];
            }
            __builtin_amdgcn_s_setprio(1);
#pragma unroll
            for (int i = 0; i < 4; ++i)
#pragma unroll
                for (int j = 0; j < 2; ++j)
                    acc[i][j] = __builtin_amdgcn_mfma_f32_16x16x32_f16(
                        afh[i], bfh[j], acc[i][j], 0, 0, 0);   // hh
#pragma unroll
            for (int i = 0; i < 4; ++i)
#pragma unroll
                for (int j = 0; j < 2; ++j)
                    acc[i][j] = __builtin_amdgcn_mfma_f32_16x16x32_f16(
                        afh[i], bfm[j], acc[i][j], 0, 0, 0);   // hm
#pragma unroll
            for (int i = 0; i < 4; ++i)
#pragma unroll
                for (int j = 0; j < 2; ++j)
                    acc[i][j] = __builtin_amdgcn_mfma_f32_16x16x32_f16(
                        afm[i], bfh[j], acc[i][j], 0, 0, 0);   // mh
            __builtin_amdgcn_s_setprio(0);
        }
    }
#undef B_STAGE
#undef A_STAGE
#undef X_LOAD

    // ---- epilogue: D layout col=lane&15, row=(lane>>4)*4+r
    float* Cz = Cp + (size_t)kz * T_TOK * E;
    const int rbase = (lane >> 4) * 4;
#pragma unroll
    for (int i = 0; i < 4; ++i)
#pragma unroll
        for (int j = 0; j < 2; ++j) {
            const int ecol = eb + wn * 32 + j * 16 + frow;
#pragma unroll
            for (int r = 0; r < 4; ++r) {
                const int tok = TB + wm * 64 + i * 16 + rbase + r;
                Cz[(size_t)tok * E + ecol] = acc[i][j][r];
            }
        }
}

// ---------------------------------------------------------------------------
// Kernel 2: fused split-K reduce + routing (proven). 16 lanes/token, 16
// experts/lane, all in registers; exact lax.top_k tie-breaks. Logits are
// scaled by 2^14 (X*64, W*256) -> multiply by 2^-14 (exact) before sigmoid.
// ---------------------------------------------------------------------------
__global__ __launch_bounds__(256) void route_kernel(const float* __restrict__ P,
                                                    const float* __restrict__ bias,
                                                    float* __restrict__ out,
                                                    int nsplit) {
    const int sub = threadIdx.x & 15;
    const int tok = blockIdx.x * 16 + (threadIdx.x >> 4);
    const int ebase = sub * 16;

    double accd[16];
#pragma unroll
    for (int i = 0; i < 16; ++i) accd[i] = 0.0;
    for (int s = 0; s < nsplit; ++s) {
        const float* base = P + (size_t)s * T_TOK * E + (size_t)tok * E + ebase;
#pragma unroll
        for (int v = 0; v < 4; ++v) {
            float4 f = *(const float4*)(base + v * 4);
            accd[v * 4 + 0] += (double)f.x; accd[v * 4 + 1] += (double)f.y;
            accd[v * 4 + 2] += (double)f.z; accd[v * 4 + 3] += (double)f.w;
        }
    }

    float us[16], sc[16];
#pragma unroll
    for (int i = 0; i < 16; ++i) {
        float lg = (float)accd[i] * (1.f / 16384.f);   // exact pow2 unscale
        double s = 1.0 / (1.0 + exp(-(double)lg));
        us[i] = (float)s;
        sc[i] = us[i] + bias[ebase + i];
    }

    float m1 = -1e30f, m2 = -1e30f;
#pragma unroll
    for (int i = 0; i < 16; ++i) {
        float s = sc[i];
        if (s > m1)      { m2 = m1; m1 = s; }
        else if (s > m2) { m2 = s; }
    }
    float pm1 = __shfl_xor(m1, 1, 16);
    float pm2 = __shfl_xor(m2, 1, 16);
    float gsum = (m1 >= pm1) ? (m1 + fmaxf(m2, pm1)) : (pm1 + fmaxf(pm2, m1));

    const int g = sub >> 1;
    int rank = 0;
#pragma unroll
    for (int h = 0; h < 8; ++h) {
        float gh = __shfl(gsum, h * 2, 16);
        if (h != g && (gh > gsum || (gh == gsum && h < g))) ++rank;
    }
    const bool sel = (rank < 4);

    unsigned used = 0;
    float myoi = 0.f, myow = 0.f;
    float wsum = 0.f;
#pragma unroll
    for (int p = 0; p < 8; ++p) {
        float bv = -1e30f; int bi = 0x7fff; float bu = 0.f;
#pragma unroll
        for (int i = 0; i < 16; ++i) {
            float v = ((used >> i) & 1u) ? -1e30f : (sel ? sc[i] : 0.0f);
            if (v > bv || (v == bv && (ebase + i) < bi)) {
                bv = v; bi = ebase + i; bu = us[i];
            }
        }
#pragma unroll
        for (int d = 1; d < 16; d <<= 1) {
            float ov = __shfl_xor(bv, d, 16);
            int   oi = __shfl_xor(bi, d, 16);
            float ou = __shfl_xor(bu, d, 16);
            if (ov > bv || (ov == bv && oi < bi)) { bv = ov; bi = oi; bu = ou; }
        }
        if ((bi >> 4) == sub) used |= 1u << (bi & 15);
        if (sub == p) { myoi = (float)bi; myow = bu; }
        wsum += bu;
    }

    const float scale = 2.5f / (wsum + 1e-20f);
    if (sub < 8) {
        out[(size_t)tok * 8 + sub] = myoi;
        out[(size_t)T_TOK * 8 + (size_t)tok * 8 + sub] = myow * scale;
    }
}

// ---------------------------------------------------------------------------
extern "C" void kernel_launch(void* const* d_in, const int* in_sizes, int n_in,
                              void* d_out, int out_size, void* d_ws, size_t ws_size,
                              hipStream_t stream) {
    const float* X = (const float*)d_in[0];   // [4,4096,2048] fp32
    const float* W = (const float*)d_in[1];   // [256,2048]   fp32
    const float* B = (const float*)d_in[2];   // [256]        fp32
    float* out     = (float*)d_out;

    const size_t WE     = (size_t)E * H;                       // 524288
    const size_t planeB = WE * sizeof(unsigned short);         // 1 MB
    const size_t chunkB = (size_t)T_TOK * E * sizeof(float);   // 16 MB

    unsigned short* Wh = (unsigned short*)d_ws;
    unsigned short* Wm = Wh + WE;
    float* part = (float*)((char*)d_ws + 2 * planeB);

    // nsplit=2: grid (2,128,2)=512 blocks = exactly 2 blocks/CU; partial
    // traffic halves vs nsplit=4. Fallback 1 if workspace is tiny.
    int nsplit = 1;
    if (ws_size >= 2 * planeB + 2 * chunkB) nsplit = 2;
    const int klen = H / nsplit;

    prep_w<<<WE / (256 * 4), 256, 0, stream>>>(W, Wh, Wm);

    dim3 gg(E / 128, T_TOK / 128, nsplit);    // (2, 128, 2) = 512 blocks
    gemm_logits<<<gg, 512, 0, stream>>>(X, Wh, Wm, part, klen);

    route_kernel<<<T_TOK / 16, 256, 0, stream>>>(part, B, out, nsplit);
}

// Round 20
// 96.490 us; speedup vs baseline: 2.2248x; 1.0795x over previous
//
#include <hip/hip_runtime.h>
#include <hip/hip_bf16.h>
#include <math.h>

static constexpr int T_TOK = 16384;   // 4*4096 tokens
static constexpr int E     = 256;     // experts
static constexpr int H     = 2048;    // hidden dim

typedef __attribute__((ext_vector_type(8))) _Float16       f16x8;
typedef __attribute__((ext_vector_type(8))) unsigned short u16x8;
typedef __attribute__((ext_vector_type(4))) float          f32x4;

// 2-way f16 split of a PRE-SCALED value: xs == h + m + eps, |eps| <~ 2^-22|xs|.
__device__ __forceinline__ void split2(float xs, unsigned short& h,
                                       unsigned short& m) {
    _Float16 hh = (_Float16)xs;        // RN f32->f16
    float fh = (float)hh;
    float r  = xs - fh;                // exact in f32
    _Float16 mm = (_Float16)r;         // RN
    h = *(unsigned short*)&hh; m = *(unsigned short*)&mm;
}

// async 16B global -> LDS (dest = wave-uniform base + lane*16)
__device__ __forceinline__ void gload_lds16(const unsigned short* g,
                                            unsigned short* l) {
    __builtin_amdgcn_global_load_lds(
        (const __attribute__((address_space(1))) unsigned int*)g,
        (__attribute__((address_space(3))) unsigned int*)l, 16, 0, 0);
}

// ---------------------------------------------------------------------------
// Kernel 0: split W*256 [256][2048] fp32 into two f16 planes (same layout).
// ---------------------------------------------------------------------------
__global__ __launch_bounds__(256) void prep_w(const float* __restrict__ W,
                                              unsigned short* __restrict__ Wh,
                                              unsigned short* __restrict__ Wm) {
    const int i = (blockIdx.x * 256 + threadIdx.x) * 4;
    float4 x = *(const float4*)(W + i);
    unsigned short h[4], m[4];
    split2(x.x * 256.f, h[0], m[0]);
    split2(x.y * 256.f, h[1], m[1]);
    split2(x.z * 256.f, h[2], m[2]);
    split2(x.w * 256.f, h[3], m[3]);
#pragma unroll
    for (int q = 0; q < 4; ++q) { Wh[i+q] = h[q]; Wm[i+q] = m[q]; }
}

// ---------------------------------------------------------------------------
// Kernel 1: partial logits via f16x2 MFMA, THREE passes (hh,hm,mh).
// R19 structure (best measured: 104.2 us total / ~92.5 us gemm, 92% of the
// 2-phase-structure ceiling) + T1 XCD-AWARE BLOCK SWIZZLE:
// the A-panel-sharing pair (x=0,y,z),(x=1,y,z) has consecutive linear ids;
// default round-robin puts them on DIFFERENT XCDs (partner's X reads = L3).
// Bijective chunked swizzle (nwg=512, 512%8==0) maps same-XCD dispatch
// slots to consecutive tiles -> the pair co-resides; X re-reads become
// L2 hits. Everything else identical to R19 (single-lever discipline).
// 512 thr = 8 waves (2M x 4N), wave 64x32, acc[4][2]=32 AGPR, BK=64,
// LDS 64 KB single-buffered, nsplit=2.
// ---------------------------------------------------------------------------
__global__ __launch_bounds__(512, 4) void gemm_logits(
        const float* __restrict__ X,
        const unsigned short* __restrict__ Wh,
        const unsigned short* __restrict__ Wm,
        float* __restrict__ Cp, int klen) {
    __shared__ __align__(16) unsigned short As[2][8][128][8];   // 32 KB
    __shared__ __align__(16) unsigned short Bs[2][8][128][8];   // 32 KB

    // ---- XCD-aware swizzle of the linear block id (bijective: 512 = 8*64)
    const int nwg  = gridDim.x * gridDim.y * gridDim.z;         // 512
    const int orig = blockIdx.x + gridDim.x * (blockIdx.y + gridDim.y * blockIdx.z);
    const int cpx  = nwg >> 3;                                  // 64
    const int wg   = (orig & 7) * cpx + (orig >> 3);
    const int bx   = wg & 1;                 // expert block 0..1
    const int by   = (wg >> 1) & 127;        // token block 0..127
    const int bz   = wg >> 8;                // split-K chunk 0..1

    const int tid  = threadIdx.x;
    const int lane = tid & 63;
    const int wid  = tid >> 6;            // 0..7
    const int wm   = wid >> 2, wn = wid & 3;   // 2M x 4N; wave = 64 x 32
    const int kbase = bz * klen;
    const int TB   = by * 128;
    const int eb   = bx * 128;

    // A staging: thread owns row=tid>>2, k-chunks sc and sc+4 (sc=tid&3)
    const int srow = tid >> 2;
    const int sc   = tid & 3;
    const float* Xp = X + (size_t)(TB + srow) * H + kbase + sc * 8;

    // B staging: 2 slots per plane: tid -> (kc=tid>>7, row=tid&127) and
    // tid+512 -> (kc+4, same row). Global source k offsets bkc*8 and +32.
    const int brow = tid & 127;
    const int bkc  = tid >> 7;            // 0..3
    const unsigned short* WB0 = Wh + (size_t)(eb + brow) * H + kbase + bkc * 8;
    const unsigned short* WB1 = Wm + (size_t)(eb + brow) * H + kbase + bkc * 8;
    const int eOffB0 = tid * 8;           // elements (16 B)
    const int eOffB1 = (tid + 512) * 8;   // kc+4, same row

    const int frow = lane & 15;
    const int fkc  = lane >> 4;           // k-chunk 0..3 within a 32-k half

    f32x4 acc[4][2];
#pragma unroll
    for (int i = 0; i < 4; ++i)
#pragma unroll
        for (int j = 0; j < 2; ++j) acc[i][j] = (f32x4){0.f, 0.f, 0.f, 0.f};

    const int NK = klen / 64;             // nsplit 2 -> 16

#define B_STAGE(KT)                                                            \
    {                                                                          \
        const int ko = (KT) * 64;                                              \
        gload_lds16(WB0 + ko,      &Bs[0][0][0][0] + eOffB0);                  \
        gload_lds16(WB0 + ko + 32, &Bs[0][0][0][0] + eOffB1);                  \
        gload_lds16(WB1 + ko,      &Bs[1][0][0][0] + eOffB0);                  \
        gload_lds16(WB1 + ko + 32, &Bs[1][0][0][0] + eOffB1);                  \
    }

    // ---- scale by 64, split2 the thread's 16 floats, write chunks sc, sc+4
#define A_STAGE()                                                              \
    {                                                                          \
        float xv[16] = {x0.x, x0.y, x0.z, x0.w, x1.x, x1.y, x1.z, x1.w,        \
                        x2.x, x2.y, x2.z, x2.w, x3.x, x3.y, x3.z, x3.w};       \
        u16x8 vh0, vm0, vh1, vm1;                                              \
        _Pragma("unroll")                                                      \
        for (int t = 0; t < 8; ++t) {                                          \
            unsigned short h, m;                                               \
            split2(xv[t] * 64.f, h, m);                                        \
            vh0[t] = h; vm0[t] = m;                                            \
        }                                                                      \
        _Pragma("unroll")                                                      \
        for (int t = 0; t < 8; ++t) {                                          \
            unsigned short h, m;                                               \
            split2(xv[8 + t] * 64.f, h, m);                                    \
            vh1[t] = h; vm1[t] = m;                                            \
        }                                                                      \
        *(u16x8*)&As[0][sc    ][srow][0] = vh0;                                \
        *(u16x8*)&As[1][sc    ][srow][0] = vm0;                                \
        *(u16x8*)&As[0][sc + 4][srow][0] = vh1;                                \
        *(u16x8*)&As[1][sc + 4][srow][0] = vm1;                                \
    }

#define X_LOAD(KT)                                                             \
    {                                                                          \
        const float* xn = Xp + (KT) * 64;                                      \
        x0 = *(const float4*)(xn + 0);   x1 = *(const float4*)(xn + 4);        \
        x2 = *(const float4*)(xn + 32);  x3 = *(const float4*)(xn + 36);       \
    }

    // ---- prologue: X(0) sync load
    float4 x0, x1, x2, x3;
    X_LOAD(0);

    for (int kt = 0; kt < NK; ++kt) {
        __syncthreads();              // prior frag reads done; X(kt) landed
        B_STAGE(kt);
        A_STAGE();                    // consumes X(kt); covers B gloads
        __syncthreads();              // B gloads + A writes visible
        if (kt + 1 < NK) X_LOAD(kt + 1);   // flies under the MFMA phase

#pragma unroll
        for (int s = 0; s < 2; ++s) {
            const int s4 = s * 4 + fkc;
            f16x8 afh[4], afm[4], bfh[2], bfm[2];
#pragma unroll
            for (int i = 0; i < 4; ++i) {
                afh[i] = *(const f16x8*)&As[0][s4][wm * 64 + i * 16 + frow][0];
                afm[i] = *(const f16x8*)&As[1][s4][wm * 64 + i * 16 + frow][0];
            }
#pragma unroll
            for (int j = 0; j < 2; ++j) {
                bfh[j] = *(const f16x8*)&Bs[0][s4][wn * 32 + j * 16 + frow][0];
                bfm[j] = *(const f16x8*)&Bs[1][s4][wn * 32 + j * 16 + frow][0];
            }
            __builtin_amdgcn_s_setprio(1);
#pragma unroll
            for (int i = 0; i < 4; ++i)
#pragma unroll
                for (int j = 0; j < 2; ++j)
                    acc[i][j] = __builtin_amdgcn_mfma_f32_16x16x32_f16(
                        afh[i], bfh[j], acc[i][j], 0, 0, 0);   // hh
#pragma unroll
            for (int i = 0; i < 4; ++i)
#pragma unroll
                for (int j = 0; j < 2; ++j)
                    acc[i][j] = __builtin_amdgcn_mfma_f32_16x16x32_f16(
                        afh[i], bfm[j], acc[i][j], 0, 0, 0);   // hm
#pragma unroll
            for (int i = 0; i < 4; ++i)
#pragma unroll
                for (int j = 0; j < 2; ++j)
                    acc[i][j] = __builtin_amdgcn_mfma_f32_16x16x32_f16(
                        afm[i], bfh[j], acc[i][j], 0, 0, 0);   // mh
            __builtin_amdgcn_s_setprio(0);
        }
    }
#undef B_STAGE
#undef A_STAGE
#undef X_LOAD

    // ---- epilogue: D layout col=lane&15, row=(lane>>4)*4+r
    float* Cz = Cp + (size_t)bz * T_TOK * E;
    const int rbase = (lane >> 4) * 4;
#pragma unroll
    for (int i = 0; i < 4; ++i)
#pragma unroll
        for (int j = 0; j < 2; ++j) {
            const int ecol = eb + wn * 32 + j * 16 + frow;
#pragma unroll
            for (int r = 0; r < 4; ++r) {
                const int tok = TB + wm * 64 + i * 16 + rbase + r;
                Cz[(size_t)tok * E + ecol] = acc[i][j][r];
            }
        }
}

// ---------------------------------------------------------------------------
// Kernel 2: fused split-K reduce + routing (proven). 16 lanes/token, 16
// experts/lane, all in registers; exact lax.top_k tie-breaks. Logits are
// scaled by 2^14 (X*64, W*256) -> multiply by 2^-14 (exact) before sigmoid.
// ---------------------------------------------------------------------------
__global__ __launch_bounds__(256) void route_kernel(const float* __restrict__ P,
                                                    const float* __restrict__ bias,
                                                    float* __restrict__ out,
                                                    int nsplit) {
    const int sub = threadIdx.x & 15;
    const int tok = blockIdx.x * 16 + (threadIdx.x >> 4);
    const int ebase = sub * 16;

    double accd[16];
#pragma unroll
    for (int i = 0; i < 16; ++i) accd[i] = 0.0;
    for (int s = 0; s < nsplit; ++s) {
        const float* base = P + (size_t)s * T_TOK * E + (size_t)tok * E + ebase;
#pragma unroll
        for (int v = 0; v < 4; ++v) {
            float4 f = *(const float4*)(base + v * 4);
            accd[v * 4 + 0] += (double)f.x; accd[v * 4 + 1] += (double)f.y;
            accd[v * 4 + 2] += (double)f.z; accd[v * 4 + 3] += (double)f.w;
        }
    }

    float us[16], sc[16];
#pragma unroll
    for (int i = 0; i < 16; ++i) {
        float lg = (float)accd[i] * (1.f / 16384.f);   // exact pow2 unscale
        double s = 1.0 / (1.0 + exp(-(double)lg));
        us[i] = (float)s;
        sc[i] = us[i] + bias[ebase + i];
    }

    float m1 = -1e30f, m2 = -1e30f;
#pragma unroll
    for (int i = 0; i < 16; ++i) {
        float s = sc[i];
        if (s > m1)      { m2 = m1; m1 = s; }
        else if (s > m2) { m2 = s; }
    }
    float pm1 = __shfl_xor(m1, 1, 16);
    float pm2 = __shfl_xor(m2, 1, 16);
    float gsum = (m1 >= pm1) ? (m1 + fmaxf(m2, pm1)) : (pm1 + fmaxf(pm2, m1));

    const int g = sub >> 1;
    int rank = 0;
#pragma unroll
    for (int h = 0; h < 8; ++h) {
        float gh = __shfl(gsum, h * 2, 16);
        if (h != g && (gh > gsum || (gh == gsum && h < g))) ++rank;
    }
    const bool sel = (rank < 4);

    unsigned used = 0;
    float myoi = 0.f, myow = 0.f;
    float wsum = 0.f;
#pragma unroll
    for (int p = 0; p < 8; ++p) {
        float bv = -1e30f; int bi = 0x7fff; float bu = 0.f;
#pragma unroll
        for (int i = 0; i < 16; ++i) {
            float v = ((used >> i) & 1u) ? -1e30f : (sel ? sc[i] : 0.0f);
            if (v > bv || (v == bv && (ebase + i) < bi)) {
                bv = v; bi = ebase + i; bu = us[i];
            }
        }
#pragma unroll
        for (int d = 1; d < 16; d <<= 1) {
            float ov = __shfl_xor(bv, d, 16);
            int   oi = __shfl_xor(bi, d, 16);
            float ou = __shfl_xor(bu, d, 16);
            if (ov > bv || (ov == bv && oi < bi)) { bv = ov; bi = oi; bu = ou; }
        }
        if ((bi >> 4) == sub) used |= 1u << (bi & 15);
        if (sub == p) { myoi = (float)bi; myow = bu; }
        wsum += bu;
    }

    const float scale = 2.5f / (wsum + 1e-20f);
    if (sub < 8) {
        out[(size_t)tok * 8 + sub] = myoi;
        out[(size_t)T_TOK * 8 + (size_t)tok * 8 + sub] = myow * scale;
    }
}

// ---------------------------------------------------------------------------
extern "C" void kernel_launch(void* const* d_in, const int* in_sizes, int n_in,
                              void* d_out, int out_size, void* d_ws, size_t ws_size,
                              hipStream_t stream) {
    const float* X = (const float*)d_in[0];   // [4,4096,2048] fp32
    const float* W = (const float*)d_in[1];   // [256,2048]   fp32
    const float* B = (const float*)d_in[2];   // [256]        fp32
    float* out     = (float*)d_out;

    const size_t WE     = (size_t)E * H;                       // 524288
    const size_t planeB = WE * sizeof(unsigned short);         // 1 MB
    const size_t chunkB = (size_t)T_TOK * E * sizeof(float);   // 16 MB

    unsigned short* Wh = (unsigned short*)d_ws;
    unsigned short* Wm = Wh + WE;
    float* part = (float*)((char*)d_ws + 2 * planeB);

    // nsplit=2: grid (2,128,2)=512 blocks = exactly 2 blocks/CU; partial
    // traffic halves vs nsplit=4. Fallback 1 if workspace is tiny.
    int nsplit = 1;
    if (ws_size >= 2 * planeB + 2 * chunkB) nsplit = 2;
    const int klen = H / nsplit;

    prep_w<<<WE / (256 * 4), 256, 0, stream>>>(W, Wh, Wm);

    dim3 gg(E / 128, T_TOK / 128, nsplit);    // (2, 128, 2) = 512 blocks
    gemm_logits<<<gg, 512, 0, stream>>>(X, Wh, Wm, part, klen);

    route_kernel<<<T_TOK / 16, 256, 0, stream>>>(part, B, out, nsplit);
}